// Round 5
// baseline (190.923 us; speedup 1.0000x reference)
//
#include <hip/hip_runtime.h>

// InterNet B=32,N=16,D=64,P=8. Factorized rel-conv:
//   conv(mask*[y1;y2],W_rel) = mask*(convA(x[o1]) + convB(x[o2]))
// 2 dispatches:
//   prep:  weights -> bf16 [tap][oc][ic]; zero per-batch barrier counters
//   fused: per image: stage x -> LDS; MFMA self/relA/relB (xs->LDS, cA/cB->global);
//          per-batch atomic barrier (release add / acquire spin + threadfence);
//          combine (mask-compacted) -> pred(LDS) -> aff conv -> a(LDS) ->
//          agg conv (128ic: [a|x]) -> out.

#define NIMG 512
#define IMGSZ 4096

using bf16x8 = __attribute__((ext_vector_type(8))) short;
using f32x4  = __attribute__((ext_vector_type(4))) float;
using u16x8  = __attribute__((ext_vector_type(8))) unsigned short;

__device__ inline unsigned short f2bf(float f) {
  union { float f; unsigned u; } v; v.f = f;
  unsigned r = v.u + 0x7fffu + ((v.u >> 16) & 1u);
  return (unsigned short)(r >> 16);
}

// Wt: convs 0..3 (self,relA,relB,aff) [9][64][64] at c*36864; agg [9][64][128] at 4*36864.
__global__ __launch_bounds__(256) void prep_weights(
    const float* __restrict__ Wr, const float* __restrict__ Ws,
    const float* __restrict__ Wa, const float* __restrict__ Wg,
    unsigned short* __restrict__ Wt, int* __restrict__ ctr)
{
  int idx = blockIdx.x * 256 + threadIdx.x;
  if (blockIdx.x == 0 && threadIdx.x < 32) ctr[threadIdx.x] = 0;  // barrier ctrs
  if (idx >= 221184) return;
  float v;
  if (idx < 147456) {
    int c = idx / 36864, r = idx % 36864;
    int t = r >> 12, oc = (r >> 6) & 63, ic = r & 63;
    switch (c) {
      case 0:  v = Ws[oc * 576 + ic * 9 + t]; break;
      case 1:  v = Wr[oc * 1152 + ic * 9 + t]; break;
      case 2:  v = Wr[oc * 1152 + (ic + 64) * 9 + t]; break;
      default: v = Wa[oc * 576 + ic * 9 + t]; break;
    }
  } else {
    int r2 = idx - 147456;
    int t = r2 >> 13, oc = (r2 >> 7) & 63, ic = r2 & 127;
    v = Wg[oc * 1152 + ic * 9 + t];
  }
  Wt[idx] = f2bf(v);
}

// batch b pinned to XCD b&7 (blockIdx%8 heuristic; perf-only). Bijective;
// each batch's 16 blocks stay inside one 128-block window (barrier progress).
__device__ inline void decode_img(int j, int& b, int& o) {
  b = ((j >> 7) << 3) | (j & 7);
  o = (j >> 3) & 15;
}

__global__ __launch_bounds__(256, 2) void fused(
    const float* __restrict__ x,
    const int* __restrict__ g_idx,
    const unsigned short* __restrict__ Wt,
    const float* __restrict__ b_rel, const float* __restrict__ b_self,
    const float* __restrict__ b_aff, const float* __restrict__ b_agg,
    float* __restrict__ cA, float* __restrict__ cB,
    int* __restrict__ ctr,
    float* __restrict__ out)
{
  constexpr int ROW = 72, ROW2 = 136, XROW = 68;
  __shared__ __align__(16) unsigned short simg2[65 * ROW2]; // [a | x] bf16
  __shared__ __align__(16) unsigned short simg[65 * ROW];   // pred bf16
  __shared__ __align__(16) float sxs[64 * XROW];            // xs fp32
  __shared__ int so1c[16], so2c[16];
  __shared__ int scnt;

  int b, i;
  decode_img(blockIdx.x, b, i);
  const int img = b * 16 + i;
  const int tid = threadIdx.x;
  const int w = tid >> 6, lane = tid & 63;

  // ---- mask compaction (wave 0): keep only m==1 pairs
  if (tid < 64) {
    int v1 = 0, v2 = 0, m = 0;
    if (tid < 15) {
      const int* gp = g_idx + ((size_t)b * 240 + i * 15 + tid) * 3;
      v1 = gp[0] & 15;   // tile(x, n-1): x1[j] = x[j % 16]
      v2 = gp[1] & 15;
      m  = gp[2];
    }
    unsigned long long bal = __ballot(m != 0);
    if (m) {
      int pos = __popcll(bal & ((1ull << tid) - 1ull));
      so1c[pos] = v1; so2c[pos] = v2;
    }
    if (tid == 0) scnt = (int)__popcll(bal);
  }

  // ---- stage x [ic][px] fp32 -> simg2 rows [px][64+ic] bf16
  {
    const int px = lane;
    const float* base = x + (size_t)img * IMGSZ;
#pragma unroll
    for (int r = 0; r < 8; ++r) {
      int ic0 = (w + 4 * r) * 2;
      const float* s = base + ic0 * 64;
      float a = s[px], c = s[64 + px];
      *(unsigned*)(simg2 + px * ROW2 + 64 + ic0) =
          (unsigned)f2bf(a) | ((unsigned)f2bf(c) << 16);
    }
  }
  if (tid < ROW2 / 2) ((unsigned*)simg2)[64 * (ROW2 / 2) + tid] = 0; // zero row
  if (tid < ROW / 2)  ((unsigned*)simg)[64 * (ROW / 2) + tid] = 0;   // zero row
  __syncthreads();

  const int q = lane >> 4, n16 = lane & 15;
  const int ocb = w * 16;
  const int co = ocb + q * 4;
  const int awoff = (ocb + n16) * 64 + q * 8;

  int pyt[4], pxt[4];
#pragma unroll
  for (int t = 0; t < 4; ++t) { int px = t * 16 + n16; pyt[t] = px >> 3; pxt[t] = px & 7; }

  // ---- phase 1: self/relA/relB convs (wave w = oc-tile w*16, all 64 px)
  {
    f32x4 aS[4] = {}, aA[4] = {}, aB[4] = {};
    const unsigned short* WS = Wt + awoff;
    const unsigned short* WA = Wt + 36864 + awoff;
    const unsigned short* WB = Wt + 2 * 36864 + awoff;
#pragma unroll
    for (int tap = 0; tap < 9; ++tap) {
      const int dy = tap / 3 - 1, dx = tap % 3 - 1;
      int spt[4];
#pragma unroll
      for (int t = 0; t < 4; ++t) {
        int sy = pyt[t] + dy, sx = pxt[t] + dx;
        spt[t] = ((unsigned)sy < 8u && (unsigned)sx < 8u) ? (sy * 8 + sx) : 64;
      }
#pragma unroll
      for (int ks = 0; ks < 2; ++ks) {
        const int wo = tap * 4096 + ks * 32;
        bf16x8 as = *(const bf16x8*)(WS + wo);
        bf16x8 aa = *(const bf16x8*)(WA + wo);
        bf16x8 ab = *(const bf16x8*)(WB + wo);
#pragma unroll
        for (int t = 0; t < 4; ++t) {
          bf16x8 bt = *(const bf16x8*)(simg2 + spt[t] * ROW2 + 64 + ks * 32 + q * 8);
          aS[t] = __builtin_amdgcn_mfma_f32_16x16x32_bf16(as, bt, aS[t], 0, 0, 0);
          aA[t] = __builtin_amdgcn_mfma_f32_16x16x32_bf16(aa, bt, aA[t], 0, 0, 0);
          aB[t] = __builtin_amdgcn_mfma_f32_16x16x32_bf16(ab, bt, aB[t], 0, 0, 0);
        }
      }
    }
    const size_t ib = (size_t)img * IMGSZ;
#pragma unroll
    for (int t = 0; t < 4; ++t) {
      int px = t * 16 + n16;
      f32x4 vs = aS[t];
#pragma unroll
      for (int r = 0; r < 4; ++r) vs[r] = fmaxf(vs[r] + b_self[co + r], 0.f);
      *(f32x4*)(sxs + px * XROW + co) = vs;           // xs stays in LDS
      *(f32x4*)(cA + ib + px * 64 + co) = aA[t];
      *(f32x4*)(cB + ib + px * 64 + co) = aB[t];
    }
  }

  // ---- per-batch barrier: release-add, acquire-spin until all 16 arrived
  __syncthreads();   // compiler drains vmcnt(0) before s_barrier: stores in L2
  if (tid == 0)
    __hip_atomic_fetch_add(ctr + b, 1, __ATOMIC_RELEASE, __HIP_MEMORY_SCOPE_AGENT);
  if (tid == 0) {
    int v;
    do {
      v = __hip_atomic_load(ctr + b, __ATOMIC_ACQUIRE, __HIP_MEMORY_SCOPE_AGENT);
      if (v < 16) __builtin_amdgcn_s_sleep(2);
    } while (v < 16);
  }
  __syncthreads();
  __threadfence();   // invalidate stale L1/L2 before reading peers' cA/cB

  // ---- phase 2a: combine; pred = xs + cnt0*relu(br) + sum_{m=1} relu(cA+cB+br)
  {
    const int e_px = tid >> 2;
    const int e_ic = (tid & 3) * 16;
    const size_t base_b = (size_t)b * 16 * IMGSZ;
    const int eo = e_px * 64 + e_ic;
    const int cnt1 = scnt, cnt0 = 15 - cnt1;
    float acc[16], br[16];
    const float* sxp = sxs + e_px * XROW + e_ic;
#pragma unroll
    for (int u = 0; u < 16; ++u) {
      br[u] = b_rel[e_ic + u];
      acc[u] = sxp[u] + (float)cnt0 * fmaxf(br[u], 0.f);
    }
    for (int j = 0; j < cnt1; ++j) {
      const f32x4* a1 = (const f32x4*)(cA + base_b + (size_t)so1c[j] * IMGSZ + eo);
      const f32x4* a2 = (const f32x4*)(cB + base_b + (size_t)so2c[j] * IMGSZ + eo);
#pragma unroll
      for (int u4 = 0; u4 < 4; ++u4) {
        f32x4 v1 = a1[u4], v2 = a2[u4];
#pragma unroll
        for (int r = 0; r < 4; ++r)
          acc[u4 * 4 + r] += fmaxf(v1[r] + v2[r] + br[u4 * 4 + r], 0.f);
      }
    }
    u16x8 p0, p1;
#pragma unroll
    for (int u = 0; u < 8; ++u) { p0[u] = f2bf(acc[u]); p1[u] = f2bf(acc[8 + u]); }
    *(u16x8*)(simg + e_px * ROW + e_ic) = p0;
    *(u16x8*)(simg + e_px * ROW + e_ic + 8) = p1;
  }
  __syncthreads();

  // ---- phase 2b: aff conv (pred -> a), a -> simg2 rows [px][ic 0..63]
  {
    f32x4 c[4] = {};
    const unsigned short* WAff = Wt + 3 * 36864 + awoff;
#pragma unroll
    for (int tap = 0; tap < 9; ++tap) {
      const int dy = tap / 3 - 1, dx = tap % 3 - 1;
      int spt[4];
#pragma unroll
      for (int t = 0; t < 4; ++t) {
        int sy = pyt[t] + dy, sx = pxt[t] + dx;
        spt[t] = ((unsigned)sy < 8u && (unsigned)sx < 8u) ? (sy * 8 + sx) : 64;
      }
#pragma unroll
      for (int ks = 0; ks < 2; ++ks) {
        bf16x8 a = *(const bf16x8*)(WAff + tap * 4096 + ks * 32);
#pragma unroll
        for (int t = 0; t < 4; ++t) {
          bf16x8 bt = *(const bf16x8*)(simg + spt[t] * ROW + ks * 32 + q * 8);
          c[t] = __builtin_amdgcn_mfma_f32_16x16x32_bf16(a, bt, c[t], 0, 0, 0);
        }
      }
    }
#pragma unroll
    for (int t = 0; t < 4; ++t) {
      int px = t * 16 + n16;
      float v0 = fmaxf(c[t][0] + b_aff[co + 0], 0.f);
      float v1 = fmaxf(c[t][1] + b_aff[co + 1], 0.f);
      float v2 = fmaxf(c[t][2] + b_aff[co + 2], 0.f);
      float v3 = fmaxf(c[t][3] + b_aff[co + 3], 0.f);
      uint2 pk;
      pk.x = (unsigned)f2bf(v0) | ((unsigned)f2bf(v1) << 16);
      pk.y = (unsigned)f2bf(v2) | ((unsigned)f2bf(v3) << 16);
      *(uint2*)(simg2 + px * ROW2 + co) = pk;
    }
  }
  __syncthreads();

  // ---- phase 2c: agg conv (128 ic: [a | x]) -> out fp32 [ic][px]
  {
    f32x4 g[4] = {};
    const unsigned short* WAgg = Wt + 4 * 36864 + (ocb + n16) * 128 + q * 8;
#pragma unroll
    for (int tap = 0; tap < 9; ++tap) {
      const int dy = tap / 3 - 1, dx = tap % 3 - 1;
      int spt[4];
#pragma unroll
      for (int t = 0; t < 4; ++t) {
        int sy = pyt[t] + dy, sx = pxt[t] + dx;
        spt[t] = ((unsigned)sy < 8u && (unsigned)sx < 8u) ? (sy * 8 + sx) : 64;
      }
#pragma unroll
      for (int ks = 0; ks < 4; ++ks) {
        bf16x8 a = *(const bf16x8*)(WAgg + tap * 8192 + ks * 32);
#pragma unroll
        for (int t = 0; t < 4; ++t) {
          bf16x8 bt = *(const bf16x8*)(simg2 + spt[t] * ROW2 + ks * 32 + q * 8);
          g[t] = __builtin_amdgcn_mfma_f32_16x16x32_bf16(a, bt, g[t], 0, 0, 0);
        }
      }
    }
    float* ob = out + (size_t)img * IMGSZ;
#pragma unroll
    for (int t = 0; t < 4; ++t) {
      int px = t * 16 + n16;
#pragma unroll
      for (int r = 0; r < 4; ++r)
        ob[(co + r) * 64 + px] = fmaxf(g[t][r] + b_agg[co + r], 0.f);
    }
  }
}

extern "C" void kernel_launch(void* const* d_in, const int* in_sizes, int n_in,
                              void* d_out, int out_size, void* d_ws, size_t ws_size,
                              hipStream_t stream) {
  const float* x      = (const float*)d_in[0];
  const int*   g_idx  = (const int*)  d_in[1];
  const float* W_rel  = (const float*)d_in[2];
  const float* b_rel  = (const float*)d_in[3];
  const float* W_self = (const float*)d_in[4];
  const float* b_self = (const float*)d_in[5];
  const float* W_aff  = (const float*)d_in[6];
  const float* b_aff  = (const float*)d_in[7];
  const float* W_agg  = (const float*)d_in[8];
  const float* b_agg  = (const float*)d_in[9];
  float* out = (float*)d_out;

  float* ws = (float*)d_ws;
  float* cA = ws;                                            // [512][64px][64ic]
  float* cB = ws + 2097152;
  unsigned short* Wt = (unsigned short*)(ws + 2 * 2097152);  // 221184 bf16
  int* ctr = (int*)(ws + 2 * 2097152 + 131072);              // 32 barrier ctrs

  prep_weights<<<864, 256, 0, stream>>>(W_rel, W_self, W_aff, W_agg, Wt, ctr);
  fused<<<NIMG, 256, 0, stream>>>(x, g_idx, Wt, b_rel, b_self, b_aff, b_agg,
                                  cA, cB, ctr, out);
}